// Round 1
// baseline (10966.991 us; speedup 1.0000x reference)
//
#include <hip/hip_runtime.h>
#include <hip/hip_bf16.h>

// Problem constants
#define NPOS 16384      // B*H*W = 16*32*32
#define DCH  128        // channels / code dim
#define KCB  8192       // codebook size
#define HW   1024       // 32*32
#define BETA 0.25f

#define ZQ_SZ 2097152   // 16*128*32*32

// ws layout (in floats):
//   zt    : [NPOS][DCH]        @ 0           (2097152)
//   csq   : [KCB]              @ 2097152     (8192)
//   bestd : [2][NPOS]          @ 2105344     (32768)
//   besti : [2][NPOS] (int)    @ 2138112     (32768)

// ---------------- Kernel A: channel-last l2 normalize ----------------
// z: (B, C, H, W) -> zt: (N, D) with zt[n] = z[b,:,h,w] / max(||.||, 1e-12)
__global__ __launch_bounds__(256) void knorm(const float* __restrict__ z,
                                             float* __restrict__ zt) {
    __shared__ __align__(16) float Xs[64 * 129];
    __shared__ float inv[64];
    const int t = threadIdx.x;
    const int n0 = blockIdx.x * 64;
    const int b = n0 >> 10;
    const int hw0 = n0 & 1023;
    const float* zb = z + (size_t)b * DCH * HW + hw0;

    const int lane = t & 63, cq = t >> 6;
    // coalesced transposed load: 64 consecutive hw per (b,c)
    for (int c0 = 0; c0 < DCH; c0 += 4) {
        int c = c0 + cq;
        Xs[lane * 129 + c] = zb[(size_t)c * HW + lane];
    }
    __syncthreads();
    if (t < 64) {
        float s = 0.f;
        #pragma unroll
        for (int j = 0; j < DCH; ++j) { float v = Xs[t * 129 + j]; s += v * v; }
        inv[t] = 1.0f / fmaxf(sqrtf(s), 1e-12f);
    }
    __syncthreads();
    const int c = t & 127, rb = t >> 7;
    for (int it = 0; it < 32; ++it) {
        int r = it * 2 + rb;
        zt[(size_t)(n0 + r) * DCH + c] = Xs[r * 129 + c] * inv[r];
    }
}

// ---------------- Kernel: codebook squared norms ----------------
__global__ __launch_bounds__(256) void kcsq(const float* __restrict__ w,
                                            float* __restrict__ csq) {
    int k = blockIdx.x * 256 + threadIdx.x;
    const float4* row = (const float4*)(w + (size_t)k * DCH);
    float s = 0.f;
    #pragma unroll
    for (int j = 0; j < 32; ++j) {
        float4 v = row[j];
        s += v.x * v.x + v.y * v.y + v.z * v.z + v.w * v.w;
    }
    csq[k] = s;
}

// ---------------- Kernel B: fused GEMM + argmin ----------------
// Each block: 128 rows x 4096 ks (half the codebook). 256 threads, 8x8 tile.
#define SB 68   // LDS row stride (floats): 16B-aligned, low-conflict
__global__ __launch_bounds__(256) void kargmin(const float* __restrict__ zt,
                                               const float* __restrict__ w,
                                               const float* __restrict__ csq,
                                               float* __restrict__ bestd,
                                               int* __restrict__ besti) {
    __shared__ __align__(16) float Xs[128 * SB];
    __shared__ __align__(16) float Ws[128 * SB];
    const int t = threadIdx.x;
    const int tile = blockIdx.x >> 1, half = blockIdx.x & 1;
    const int n0 = tile * 128;
    const int kbase = half * 4096;
    const int tr = t & 15, tc = t >> 4;      // compute mapping
    const int sc = (t & 15) * 4, sr = t >> 4; // staging mapping

    float best_d[8];
    int best_i[8];
    #pragma unroll
    for (int j = 0; j < 8; ++j) { best_d[j] = 3.4e38f; best_i[j] = 0; }

    for (int kb = 0; kb < 32; ++kb) {
        float acc[8][8];
        #pragma unroll
        for (int j = 0; j < 8; ++j)
            #pragma unroll
            for (int i = 0; i < 8; ++i) acc[j][i] = 0.f;

        for (int dc = 0; dc < 2; ++dc) {
            __syncthreads();   // protect previous tiles until all readers done
            #pragma unroll
            for (int m = 0; m < 8; ++m) {
                int r = sr + 16 * m;
                *(float4*)&Xs[r * SB + sc] =
                    *(const float4*)&zt[(size_t)(n0 + r) * DCH + dc * 64 + sc];
                *(float4*)&Ws[r * SB + sc] =
                    *(const float4*)&w[(size_t)(kbase + kb * 128 + r) * DCH + dc * 64 + sc];
            }
            __syncthreads();
            #pragma unroll
            for (int d4 = 0; d4 < 16; ++d4) {
                float4 xv[8];
                #pragma unroll
                for (int j = 0; j < 8; ++j)
                    xv[j] = *(float4*)&Xs[(16 * j + tr) * SB + d4 * 4];
                #pragma unroll
                for (int i = 0; i < 8; ++i) {
                    float4 wv = *(float4*)&Ws[(16 * i + tc) * SB + d4 * 4];
                    #pragma unroll
                    for (int j = 0; j < 8; ++j)
                        acc[j][i] += xv[j].x * wv.x + xv[j].y * wv.y +
                                     xv[j].z * wv.z + xv[j].w * wv.w;
                }
            }
        }
        // argmin update (k ascending within thread -> strict < keeps first min)
        #pragma unroll
        for (int i = 0; i < 8; ++i) {
            int kg = kbase + kb * 128 + 16 * i + tc;
            float cs = csq[kg];
            #pragma unroll
            for (int j = 0; j < 8; ++j) {
                float dist = cs - 2.0f * acc[j][i];
                if (dist < best_d[j]) { best_d[j] = dist; best_i[j] = kg; }
            }
        }
    }
    __syncthreads();
    // cross-thread (tc) reduction via LDS reuse
    float* red_d = Xs;          // [128][16]
    int* red_i = (int*)Ws;      // [128][16]
    #pragma unroll
    for (int j = 0; j < 8; ++j) {
        int r = 16 * j + tr;
        red_d[r * 16 + tc] = best_d[j];
        red_i[r * 16 + tc] = best_i[j];
    }
    __syncthreads();
    if (t < 128) {
        float bd = 3.4e38f; int bi = 0x7fffffff;
        for (int c = 0; c < 16; ++c) {
            float dd = red_d[t * 16 + c];
            int ii = red_i[t * 16 + c];
            if (dd < bd || (dd == bd && ii < bi)) { bd = dd; bi = ii; }
        }
        bestd[half * NPOS + n0 + t] = bd;
        besti[half * NPOS + n0 + t] = bi;
    }
}

// ---------------- Kernel C: gather + straight-through + loss + outputs ----------------
__global__ __launch_bounds__(256) void kout(const float* __restrict__ zt,
                                            const float* __restrict__ w,
                                            const float* __restrict__ bestd,
                                            const int* __restrict__ besti,
                                            float* __restrict__ out) {
    __shared__ __align__(16) float Wl[64 * 132];
    __shared__ float Ot[64 * 129];
    __shared__ int ki[64];
    __shared__ float redsum[4];
    const int t = threadIdx.x;
    const int n0 = blockIdx.x * 64;
    const int b = n0 >> 10, hw0 = n0 & 1023;

    if (t < 64) {
        int n = n0 + t;
        float d0 = bestd[n], d1 = bestd[NPOS + n];
        int i0 = besti[n], i1 = besti[NPOS + n];
        int k = (d1 < d0) ? i1 : i0;   // tie -> i0 (lower index)
        ki[t] = k;
        out[ZQ_SZ + 1 + n] = (float)k; // encoding_indices as float
    }
    __syncthreads();
    // stage the 64 selected codebook rows
    {
        int r = t >> 2, c0 = (t & 3) * 4;
        const float* wr = w + (size_t)ki[r] * DCH;
        #pragma unroll
        for (int m = 0; m < 8; ++m)
            *(float4*)&Wl[r * 132 + c0 + 16 * m] = *(const float4*)&wr[c0 + 16 * m];
    }
    __syncthreads();
    float sq = 0.f;
    {
        int c = t & 127, rb = t >> 7;
        for (int it = 0; it < 32; ++it) {
            int r = it * 2 + rb;
            float zv = zt[(size_t)(n0 + r) * DCH + c];
            float diff = Wl[r * 132 + c] - zv;  // z_q - zt
            Ot[r * 129 + c] = zv + diff;        // straight-through forward value
            sq += diff * diff;
        }
    }
    // block reduction of sq
    #pragma unroll
    for (int o = 32; o > 0; o >>= 1) sq += __shfl_down(sq, o, 64);
    if ((t & 63) == 0) redsum[t >> 6] = sq;
    __syncthreads();
    // transposed coalesced write to (B, C, H, W)
    {
        int lane = t & 63, wv = t >> 6;
        float* ob = out + (size_t)b * DCH * HW + hw0;
        for (int m = 0; m < 32; ++m) {
            int c = wv + m * 4;
            ob[(size_t)c * HW + lane] = Ot[lane * 129 + c];
        }
    }
    if (t == 0) {
        float s = redsum[0] + redsum[1] + redsum[2] + redsum[3];
        atomicAdd(out + ZQ_SZ, s * (BETA / (float)ZQ_SZ));
    }
}

extern "C" void kernel_launch(void* const* d_in, const int* in_sizes, int n_in,
                              void* d_out, int out_size, void* d_ws, size_t ws_size,
                              hipStream_t stream) {
    const float* z = (const float*)d_in[0];
    const float* w = (const float*)d_in[1];
    float* out = (float*)d_out;
    float* ws = (float*)d_ws;

    float* zt = ws;                                  // 2097152
    float* csq = ws + 2097152;                       // 8192
    float* bestd = ws + 2097152 + 8192;              // 32768
    int* besti = (int*)(ws + 2097152 + 8192 + 32768);// 32768

    knorm<<<256, 256, 0, stream>>>(z, zt);
    kcsq<<<32, 256, 0, stream>>>(w, csq);
    hipMemsetAsync(out + ZQ_SZ, 0, 4, stream);       // zero the loss slot
    kargmin<<<256, 256, 0, stream>>>(zt, w, csq, bestd, besti);
    kout<<<256, 256, 0, stream>>>(zt, w, bestd, besti, out);
}

// Round 2
// 341.261 us; speedup vs baseline: 32.1366x; 32.1366x over previous
//
#include <hip/hip_runtime.h>
#include <hip/hip_bf16.h>

typedef unsigned int u32;
typedef unsigned long long u64;
typedef unsigned short u16;

#define NPOS 16384      // B*H*W
#define DCH  128
#define KCB  8192
#define HW   1024
#define BETA 0.25f
#define ZQ_SZ 2097152
#define MARGIN 0.018f

typedef __attribute__((ext_vector_type(8))) short short8;
typedef __attribute__((ext_vector_type(4))) float f32x4;

#define GLOAD16(G, L) __builtin_amdgcn_global_load_lds( \
    (const __attribute__((address_space(1))) u32*)(const void*)(G), \
    (__attribute__((address_space(3))) u32*)(void*)(L), 16, 0, 0)

__device__ inline u16 f2bf(float x) {   // RNE float->bf16
    u32 u = __float_as_uint(x);
    u32 r = (u + 0x7FFFu + ((u >> 16) & 1u)) >> 16;
    return (u16)r;
}

__device__ inline u64 shflxor_u64(u64 v, int m) {
    u32 lo = (u32)v, hi = (u32)(v >> 32);
    lo = (u32)__shfl_xor((int)lo, m, 64);
    hi = (u32)__shfl_xor((int)hi, m, 64);
    return ((u64)hi << 32) | lo;
}

// ---------------- Kernel A: channel-last l2 normalize (+ bf16 copy) ----------------
__global__ __launch_bounds__(256) void knorm(const float* __restrict__ z,
                                             float* __restrict__ zt,
                                             u16* __restrict__ ztb) {
    __shared__ __align__(16) float Xs[64 * 129];
    __shared__ float inv[64];
    const int t = threadIdx.x;
    const int n0 = blockIdx.x * 64;
    const int b = n0 >> 10;
    const int hw0 = n0 & 1023;
    const float* zb = z + (size_t)b * DCH * HW + hw0;

    const int lane = t & 63, cq = t >> 6;
    for (int c0 = 0; c0 < DCH; c0 += 4) {
        int c = c0 + cq;
        Xs[lane * 129 + c] = zb[(size_t)c * HW + lane];
    }
    __syncthreads();
    if (t < 64) {
        float s = 0.f;
        #pragma unroll
        for (int j = 0; j < DCH; ++j) { float v = Xs[t * 129 + j]; s += v * v; }
        inv[t] = 1.0f / fmaxf(sqrtf(s), 1e-12f);
    }
    __syncthreads();
    const int c = t & 127, rb = t >> 7;
    for (int it = 0; it < 32; ++it) {
        int r = it * 2 + rb;
        float v = Xs[r * 129 + c] * inv[r];
        zt[(size_t)(n0 + r) * DCH + c] = v;
        ztb[(size_t)(n0 + r) * DCH + c] = f2bf(v);
    }
}

// ---------------- codebook squared norms ----------------
__global__ __launch_bounds__(256) void kcsq(const float* __restrict__ w,
                                            float* __restrict__ csq) {
    int k = blockIdx.x * 256 + threadIdx.x;
    const float4* row = (const float4*)(w + (size_t)k * DCH);
    float s = 0.f;
    #pragma unroll
    for (int j = 0; j < 32; ++j) {
        float4 v = row[j];
        s += v.x * v.x + v.y * v.y + v.z * v.z + v.w * v.w;
    }
    csq[k] = s;
}

// ---------------- codebook fp32 -> bf16 ----------------
__global__ __launch_bounds__(256) void kconv(const float* __restrict__ w,
                                             u16* __restrict__ wb) {
    int g = blockIdx.x * 256 + threadIdx.x;      // 131072 threads, 8 elems each
    const float4* src = (const float4*)w + (size_t)g * 2;
    float4 a = src[0], b = src[1];
    union { u16 h[8]; uint4 v; } u;
    u.h[0] = f2bf(a.x); u.h[1] = f2bf(a.y); u.h[2] = f2bf(a.z); u.h[3] = f2bf(a.w);
    u.h[4] = f2bf(b.x); u.h[5] = f2bf(b.y); u.h[6] = f2bf(b.z); u.h[7] = f2bf(b.w);
    ((uint4*)wb)[g] = u.v;
}

// ---------------- MFMA distance GEMM: PASS 0 = approx argmin, PASS 1 = repair ----------------
// Block: 128 rows (zt) x 128 codes, K=128 in one shot. 4 waves as 2x2 of 64x64.
template<int PASS>
__global__ __launch_bounds__(256) void kgemm(const u16* __restrict__ ztb,
                                             const u16* __restrict__ wbm,
                                             const float* __restrict__ csq,
                                             const float* __restrict__ zt,
                                             const float* __restrict__ wgt,
                                             u64* __restrict__ keyA,
                                             u64* __restrict__ keyB) {
    __shared__ __align__(16) u16 Xs[128 * 128];
    __shared__ __align__(16) u16 Wsh[128 * 128];
    __shared__ u64 red[2][128];
    __shared__ float rmin[128];
    const int t = threadIdx.x;
    const int bid = blockIdx.x;
    const int n0 = (bid >> 6) * 128;          // row tile
    const int k0 = (bid & 63) * 128;          // code tile
    const int w = t >> 6, lane = t & 63;
    const int wr = w >> 1, wc = w & 1;
    const int lr = lane & 15, lk = lane >> 4;

    if (PASS == 1 && t < 128) {
        u64 k = keyA[n0 + t];
        rmin[t] = __uint_as_float((u32)(k >> 32)) + MARGIN;
    }

    // stage both tiles: linear LDS dest, pre-swizzled global source (T2/m173)
    {
        const int rbase = w * 32;
        #pragma unroll
        for (int q = 0; q < 8; ++q) {
            int r = rbase + q * 4 + lk;
            int cb = lr ^ (r & 7);
            GLOAD16(ztb + (size_t)(n0 + r) * 128 + cb * 8, &Xs[(rbase + q * 4) * 128]);
        }
        #pragma unroll
        for (int q = 0; q < 8; ++q) {
            int r = rbase + q * 4 + lk;
            int cb = lr ^ (r & 7);
            GLOAD16(wbm + (size_t)(k0 + r) * 128 + cb * 8, &Wsh[(rbase + q * 4) * 128]);
        }
    }
    __syncthreads();

    f32x4 acc[4][4] = {};
    #pragma unroll
    for (int ks = 0; ks < 4; ++ks) {
        short8 av[4], bv[4];
        #pragma unroll
        for (int mi = 0; mi < 4; ++mi) {
            int row = wr * 64 + mi * 16 + lr;
            int cb = (ks * 4 + lk) ^ (row & 7);
            av[mi] = *(const short8*)&Xs[row * 128 + cb * 8];
        }
        #pragma unroll
        for (int ni = 0; ni < 4; ++ni) {
            int row = wc * 64 + ni * 16 + lr;
            int cb = (ks * 4 + lk) ^ (row & 7);
            bv[ni] = *(const short8*)&Wsh[row * 128 + cb * 8];
        }
        #pragma unroll
        for (int mi = 0; mi < 4; ++mi)
            #pragma unroll
            for (int ni = 0; ni < 4; ++ni)
                acc[mi][ni] = __builtin_amdgcn_mfma_f32_16x16x32_bf16(
                    av[mi], bv[ni], acc[mi][ni], 0, 0, 0);
    }

    float csq4[4];
    #pragma unroll
    for (int ni = 0; ni < 4; ++ni) csq4[ni] = csq[k0 + wc * 64 + ni * 16 + lr];

    if (PASS == 0) {
        // C layout (m89): col = lane&15, row = (lane>>4)*4 + reg
        #pragma unroll
        for (int mi = 0; mi < 4; ++mi) {
            #pragma unroll
            for (int reg = 0; reg < 4; ++reg) {
                u64 best = ~0ULL;
                #pragma unroll
                for (int ni = 0; ni < 4; ++ni) {
                    float dist = csq4[ni] - 2.0f * acc[mi][ni][reg] + 4.0f;
                    u64 key = (((u64)__float_as_uint(dist)) << 32)
                              | (u32)(k0 + wc * 64 + ni * 16 + lr);
                    if (key < best) best = key;
                }
                #pragma unroll
                for (int m = 1; m <= 8; m <<= 1) {
                    u64 o = shflxor_u64(best, m);
                    if (o < best) best = o;
                }
                if (lr == 0) red[wc][wr * 64 + mi * 16 + lk * 4 + reg] = best;
            }
        }
        __syncthreads();
        if (t < 128) {
            u64 a = red[0][t], b = red[1][t];
            u64 mine = a < b ? a : b;
            if (mine < keyA[n0 + t]) atomicMin(&keyA[n0 + t], mine);
        }
    } else {
        #pragma unroll
        for (int mi = 0; mi < 4; ++mi) {
            #pragma unroll
            for (int reg = 0; reg < 4; ++reg) {
                int rl = wr * 64 + mi * 16 + lk * 4 + reg;
                float thr = rmin[rl];
                #pragma unroll
                for (int ni = 0; ni < 4; ++ni) {
                    float dist = csq4[ni] - 2.0f * acc[mi][ni][reg] + 4.0f;
                    if (dist <= thr) {
                        int gr = n0 + rl;
                        int gc = k0 + wc * 64 + ni * 16 + lr;
                        const float4* xr = (const float4*)(zt + (size_t)gr * 128);
                        const float4* wv = (const float4*)(wgt + (size_t)gc * 128);
                        float s = 0.f;
                        #pragma unroll 8
                        for (int j = 0; j < 32; ++j) {
                            float4 a = xr[j], b = wv[j];
                            s = fmaf(a.x, b.x, s); s = fmaf(a.y, b.y, s);
                            s = fmaf(a.z, b.z, s); s = fmaf(a.w, b.w, s);
                        }
                        float ed = csq[gc] - 2.0f * s + 4.0f;
                        u64 key = (((u64)__float_as_uint(ed)) << 32) | (u32)gc;
                        if (key < keyB[gr]) atomicMin(&keyB[gr], key);
                    }
                }
            }
        }
    }
}

// ---------------- gather + straight-through + loss + outputs ----------------
__global__ __launch_bounds__(256) void kout(const float* __restrict__ zt,
                                            const float* __restrict__ w,
                                            const u64* __restrict__ keyB,
                                            float* __restrict__ out) {
    __shared__ __align__(16) float Wl[64 * 132];
    __shared__ float Ot[64 * 129];
    __shared__ int ki[64];
    __shared__ float redsum[4];
    const int t = threadIdx.x;
    const int n0 = blockIdx.x * 64;
    const int b = n0 >> 10, hw0 = n0 & 1023;

    if (t < 64) {
        int n = n0 + t;
        int k = (int)(u32)(keyB[n] & 0xFFFFFFFFu);
        ki[t] = k;
        out[ZQ_SZ + 1 + n] = (float)k;
    }
    __syncthreads();
    {
        int r = t >> 2, c0 = (t & 3) * 4;
        const float* wr = w + (size_t)ki[r] * DCH;
        #pragma unroll
        for (int m = 0; m < 8; ++m)
            *(float4*)&Wl[r * 132 + c0 + 16 * m] = *(const float4*)&wr[c0 + 16 * m];
    }
    __syncthreads();
    float sq = 0.f;
    {
        int c = t & 127, rb = t >> 7;
        for (int it = 0; it < 32; ++it) {
            int r = it * 2 + rb;
            float zv = zt[(size_t)(n0 + r) * DCH + c];
            float diff = Wl[r * 132 + c] - zv;
            Ot[r * 129 + c] = zv + diff;
            sq += diff * diff;
        }
    }
    #pragma unroll
    for (int o = 32; o > 0; o >>= 1) sq += __shfl_down(sq, o, 64);
    if ((t & 63) == 0) redsum[t >> 6] = sq;
    __syncthreads();
    {
        int lane = t & 63, wv = t >> 6;
        float* ob = out + (size_t)b * DCH * HW + hw0;
        for (int m = 0; m < 32; ++m) {
            int c = wv + m * 4;
            ob[(size_t)c * HW + lane] = Ot[lane * 129 + c];
        }
    }
    if (t == 0) {
        float s = redsum[0] + redsum[1] + redsum[2] + redsum[3];
        atomicAdd(out + ZQ_SZ, s * (BETA / (float)ZQ_SZ));
    }
}

extern "C" void kernel_launch(void* const* d_in, const int* in_sizes, int n_in,
                              void* d_out, int out_size, void* d_ws, size_t ws_size,
                              hipStream_t stream) {
    const float* z = (const float*)d_in[0];
    const float* w = (const float*)d_in[1];
    float* out = (float*)d_out;
    float* wsf = (float*)d_ws;

    // ws layout (floats): zt[2097152] | ztb(u16 x 2097152 = 1048576f) |
    //                     wb(u16 x 1048576 = 524288f) | csq[8192] | keyA/keyB u64[16384] each
    float* zt  = wsf;
    u16*   ztb = (u16*)(wsf + 2097152);
    u16*   wb  = (u16*)(wsf + 2097152 + 1048576);
    float* csq = wsf + 2097152 + 1048576 + 524288;
    u64*   keyA = (u64*)(csq + 8192);
    u64*   keyB = keyA + NPOS;

    knorm<<<256, 256, 0, stream>>>(z, zt, ztb);
    kcsq<<<32, 256, 0, stream>>>(w, csq);
    kconv<<<512, 256, 0, stream>>>(w, wb);
    hipMemsetAsync(keyA, 0xFF, (size_t)NPOS * 8 * 2, stream);   // keyA + keyB
    hipMemsetAsync(out + ZQ_SZ, 0, 4, stream);                  // loss slot
    kgemm<0><<<8192, 256, 0, stream>>>(ztb, wb, csq, zt, w, keyA, keyB);
    kgemm<1><<<8192, 256, 0, stream>>>(ztb, wb, csq, zt, w, keyA, keyB);
    kout<<<256, 256, 0, stream>>>(zt, w, keyB, out);
}

// Round 3
// 258.351 us; speedup vs baseline: 42.4500x; 1.3209x over previous
//
#include <hip/hip_runtime.h>
#include <hip/hip_bf16.h>

typedef unsigned int u32;
typedef unsigned long long u64;
typedef unsigned short u16;

#define NPOS 16384      // B*H*W
#define DCH  128
#define KCB  8192
#define HW   1024
#define BETA 0.25f
#define ZQ_SZ 2097152
#define MARGIN 0.024f   // >= 2*delta_bf16 (0.0157) + key quantization (0.004) + csq drop
#define QCAP 4096
#define ZSTR 132        // zt LDS row stride in floats (16B aligned, padded)

typedef __attribute__((ext_vector_type(8))) short short8;
typedef __attribute__((ext_vector_type(4))) float f32x4;

#define GLOAD16(G, L) __builtin_amdgcn_global_load_lds( \
    (const __attribute__((address_space(1))) u32*)(const void*)(G), \
    (__attribute__((address_space(3))) u32*)(void*)(L), 16, 0, 0)

__device__ inline u16 f2bf(float x) {   // RNE float->bf16
    u32 u = __float_as_uint(x);
    return (u16)((u + 0x7FFFu + ((u >> 16) & 1u)) >> 16);
}
__device__ inline u32 mono(float f) {   // monotone float->u32 (total order)
    u32 b = __float_as_uint(f);
    return (b & 0x80000000u) ? ~b : (b | 0x80000000u);
}
__device__ inline u32 umin2(u32 a, u32 b) { return a < b ? a : b; }

// ---------------- codebook prep: bf16 convert + squared norms ----------------
__global__ __launch_bounds__(256) void kwprep(const float* __restrict__ w,
                                              u16* __restrict__ wb,
                                              float* __restrict__ csq) {
    const int t = threadIdx.x;
    const int row = blockIdx.x * 16 + (t >> 4);
    const int l = t & 15;
    const float4* src = (const float4*)(w + (size_t)row * DCH + l * 8);
    float4 a = src[0], b = src[1];
    float s = a.x*a.x + a.y*a.y + a.z*a.z + a.w*a.w
            + b.x*b.x + b.y*b.y + b.z*b.z + b.w*b.w;
    union { u16 h[8]; uint4 v; } u;
    u.h[0]=f2bf(a.x); u.h[1]=f2bf(a.y); u.h[2]=f2bf(a.z); u.h[3]=f2bf(a.w);
    u.h[4]=f2bf(b.x); u.h[5]=f2bf(b.y); u.h[6]=f2bf(b.z); u.h[7]=f2bf(b.w);
    *(uint4*)(wb + (size_t)row * DCH + l * 8) = u.v;
    s += __shfl_xor(s, 1, 64);
    s += __shfl_xor(s, 2, 64);
    s += __shfl_xor(s, 4, 64);
    s += __shfl_xor(s, 8, 64);
    if (l == 0) csq[row] = s;
}

// ---------------- fused main: normalize + 2-sweep argmin + exact repair + outputs ----
__global__ __launch_bounds__(256, 1) void kmain(const float* __restrict__ z,
                                                const float* __restrict__ wgt,
                                                const u16* __restrict__ wb,
                                                const float* __restrict__ csq,
                                                float* __restrict__ out) {
    __shared__ __align__(16) u16 Wb[2][128 * 128];      // 64 KB W double buffer
    __shared__ __align__(16) float ztl[64 * ZSTR];      // 33 KB fp32 normalized rows
    __shared__ u32 queue[QCAP];                         // 16 KB candidate queue
    __shared__ u32 rowkeyW[4][64];
    __shared__ float thrL[64];
    __shared__ u64 finalkey[64];
    __shared__ float psum[64][4];
    __shared__ float invL[64];
    __shared__ float lsum[4];
    __shared__ int qcnt;

    const int t = threadIdx.x;
    const int lane = t & 63;
    const int w = t >> 6;                 // wave id 0..3
    const int n0 = blockIdx.x * 64;
    const int b = n0 >> 10, hw0 = n0 & 1023;

    // ---- phase 0: load + l2-normalize this block's 64 rows into LDS ----
    const int p = lane;                   // position within the 64-row tile
    float vch[32];
    {
        const float* zp = z + (size_t)b * DCH * HW + hw0 + p;
        #pragma unroll
        for (int j = 0; j < 32; ++j)
            vch[j] = zp[(size_t)(w * 32 + j) * HW];
        float s = 0.f;
        #pragma unroll
        for (int j = 0; j < 32; ++j) s += vch[j] * vch[j];
        psum[p][w] = s;
    }
    __syncthreads();
    if (t < 64) {
        float ss = psum[t][0] + psum[t][1] + psum[t][2] + psum[t][3];
        invL[t] = 1.0f / fmaxf(sqrtf(ss), 1e-12f);
    }
    __syncthreads();
    {
        float inv = invL[p];
        #pragma unroll
        for (int j = 0; j < 32; ++j)
            ztl[p * ZSTR + w * 32 + j] = vch[j] * inv;
    }
    if (t == 0) qcnt = 0;
    if (t < 64) finalkey[t] = ~0ULL;
    __syncthreads();

    // ---- A fragments (bf16) held in registers for both sweeps ----
    // mfma_f32_16x16x32_bf16: A row = lane&15, k = (lane>>4)*8 + j  (round-2 verified)
    short8 af[4][4];
    #pragma unroll
    for (int rt = 0; rt < 4; ++rt)
        #pragma unroll
        for (int ks = 0; ks < 4; ++ks) {
            int row = rt * 16 + (lane & 15);
            int kb = ks * 32 + (lane >> 4) * 8;
            const float4* zr = (const float4*)&ztl[row * ZSTR + kb];
            float4 x0 = zr[0], x1 = zr[1];
            union { u16 h[8]; short8 v; } uu;
            uu.h[0]=f2bf(x0.x); uu.h[1]=f2bf(x0.y); uu.h[2]=f2bf(x0.z); uu.h[3]=f2bf(x0.w);
            uu.h[4]=f2bf(x1.x); uu.h[5]=f2bf(x1.y); uu.h[6]=f2bf(x1.z); uu.h[7]=f2bf(x1.w);
            af[rt][ks] = uu.v;
        }

    // staging: linear LDS dest, pre-swizzled global source (16B-block XOR row&7)
    #define STAGE(BUF, KT) do { \
        const u16* wsrc = wb + (size_t)(KT) * (128 * 128); \
        const int rb_ = w * 32; \
        _Pragma("unroll") \
        for (int q = 0; q < 8; ++q) { \
            int rr = rb_ + q * 4 + (lane >> 4); \
            int gblk = (lane & 15) ^ (rr & 7); \
            GLOAD16(wsrc + rr * 128 + gblk * 8, &Wb[BUF][(rb_ + q * 4) * 128]); \
        } \
    } while (0)

    u32 bkey[16];
    #pragma unroll
    for (int i = 0; i < 16; ++i) bkey[i] = 0xFFFFFFFFu;

    // ================= SWEEP 1: approx distances, per-row running min =================
    STAGE(0, 0);
    __syncthreads();
    for (int kt = 0; kt < 64; ++kt) {
        int cur = kt & 1;
        if (kt < 63) STAGE(cur ^ 1, kt + 1);
        short8 bv[2][4];
        #pragma unroll
        for (int ct = 0; ct < 2; ++ct)
            #pragma unroll
            for (int ks = 0; ks < 4; ++ks) {
                int c = w * 32 + ct * 16 + (lane & 15);
                int blk = ks * 4 + (lane >> 4);
                int sb = blk ^ (c & 7);
                bv[ct][ks] = *(const short8*)&Wb[cur][c * 128 + sb * 8];
            }
        f32x4 acc[4][2] = {};
        #pragma unroll
        for (int ks = 0; ks < 4; ++ks)
            #pragma unroll
            for (int rt = 0; rt < 4; ++rt) {
                acc[rt][0] = __builtin_amdgcn_mfma_f32_16x16x32_bf16(af[rt][ks], bv[0][ks], acc[rt][0], 0, 0, 0);
                acc[rt][1] = __builtin_amdgcn_mfma_f32_16x16x32_bf16(af[rt][ks], bv[1][ks], acc[rt][1], 0, 0, 0);
            }
        u32 cb0 = (u32)(kt * 128 + w * 32 + (lane & 15));
        #pragma unroll
        for (int rt = 0; rt < 4; ++rt)
            #pragma unroll
            for (int e = 0; e < 4; ++e) {
                float d0 = fmaxf(fmaf(acc[rt][0][e], -2.f, 2.f), 0.f);
                float d1 = fmaxf(fmaf(acc[rt][1][e], -2.f, 2.f), 0.f);
                u32 k0 = (__float_as_uint(d0) & 0xFFFFE000u) | cb0;
                u32 k1 = (__float_as_uint(d1) & 0xFFFFE000u) | (cb0 + 16u);
                int i = rt * 4 + e;
                bkey[i] = umin2(bkey[i], umin2(k0, k1));
            }
        __syncthreads();
    }
    // per-row reduce: row held by 16 lanes (lane&15); reduce over 4 xor bits
    #pragma unroll
    for (int i = 0; i < 16; ++i) {
        u32 k = bkey[i];
        k = umin2(k, (u32)__shfl_xor((int)k, 1, 64));
        k = umin2(k, (u32)__shfl_xor((int)k, 2, 64));
        k = umin2(k, (u32)__shfl_xor((int)k, 4, 64));
        k = umin2(k, (u32)__shfl_xor((int)k, 8, 64));
        bkey[i] = k;
    }
    if ((lane & 15) == 0) {
        int q4 = lane >> 4;
        #pragma unroll
        for (int i = 0; i < 16; ++i) {
            int rt = i >> 2, e = i & 3;
            rowkeyW[w][rt * 16 + q4 * 4 + e] = bkey[i];
        }
    }
    __syncthreads();
    if (t < 64) {
        u32 m = umin2(umin2(rowkeyW[0][t], rowkeyW[1][t]),
                      umin2(rowkeyW[2][t], rowkeyW[3][t]));
        thrL[t] = __uint_as_float(m & 0xFFFFE000u) + MARGIN;
    }
    __syncthreads();

    float thr[16];
    #pragma unroll
    for (int i = 0; i < 16; ++i) {
        int rt = i >> 2, e = i & 3;
        thr[i] = thrL[rt * 16 + (lane >> 4) * 4 + e];
    }

    // ================= SWEEP 2: re-run, collect candidates within margin =============
    STAGE(0, 0);
    __syncthreads();
    for (int kt = 0; kt < 64; ++kt) {
        int cur = kt & 1;
        if (kt < 63) STAGE(cur ^ 1, kt + 1);
        short8 bv[2][4];
        #pragma unroll
        for (int ct = 0; ct < 2; ++ct)
            #pragma unroll
            for (int ks = 0; ks < 4; ++ks) {
                int c = w * 32 + ct * 16 + (lane & 15);
                int blk = ks * 4 + (lane >> 4);
                int sb = blk ^ (c & 7);
                bv[ct][ks] = *(const short8*)&Wb[cur][c * 128 + sb * 8];
            }
        f32x4 acc[4][2] = {};
        #pragma unroll
        for (int ks = 0; ks < 4; ++ks)
            #pragma unroll
            for (int rt = 0; rt < 4; ++rt) {
                acc[rt][0] = __builtin_amdgcn_mfma_f32_16x16x32_bf16(af[rt][ks], bv[0][ks], acc[rt][0], 0, 0, 0);
                acc[rt][1] = __builtin_amdgcn_mfma_f32_16x16x32_bf16(af[rt][ks], bv[1][ks], acc[rt][1], 0, 0, 0);
            }
        u32 cb0 = (u32)(kt * 128 + w * 32 + (lane & 15));
        #pragma unroll
        for (int rt = 0; rt < 4; ++rt)
            #pragma unroll
            for (int e = 0; e < 4; ++e) {
                float d0 = fmaf(acc[rt][0][e], -2.f, 2.f);
                float d1 = fmaf(acc[rt][1][e], -2.f, 2.f);
                float th = thr[rt * 4 + e];
                if (d0 <= th) {
                    int rl = rt * 16 + (lane >> 4) * 4 + e;
                    int qi = atomicAdd(&qcnt, 1);
                    if (qi < QCAP) queue[qi] = ((u32)rl << 13) | cb0;
                }
                if (d1 <= th) {
                    int rl = rt * 16 + (lane >> 4) * 4 + e;
                    int qi = atomicAdd(&qcnt, 1);
                    if (qi < QCAP) queue[qi] = ((u32)rl << 13) | (cb0 + 16u);
                }
            }
        __syncthreads();
    }

    // ---- exact fp32 repair: one candidate per 16-lane group ----
    {
        int nq = qcnt < QCAP ? qcnt : QCAP;
        int gq = t >> 4, l = t & 15;
        for (int qi = gq; qi < nq; qi += 16) {
            u32 e = queue[qi];
            int rl = e >> 13;
            int code = e & 0x1FFF;
            const float4* zr = (const float4*)&ztl[rl * ZSTR + l * 8];
            const float4* wr = (const float4*)(wgt + (size_t)code * DCH + l * 8);
            float4 za = zr[0], zb = zr[1], wa = wr[0], wbv = wr[1];
            float s = 0.f;
            s = fmaf(za.x, wa.x, s); s = fmaf(za.y, wa.y, s);
            s = fmaf(za.z, wa.z, s); s = fmaf(za.w, wa.w, s);
            s = fmaf(zb.x, wbv.x, s); s = fmaf(zb.y, wbv.y, s);
            s = fmaf(zb.z, wbv.z, s); s = fmaf(zb.w, wbv.w, s);
            s += __shfl_xor(s, 1, 64);
            s += __shfl_xor(s, 2, 64);
            s += __shfl_xor(s, 4, 64);
            s += __shfl_xor(s, 8, 64);
            if (l == 0) {
                float ed = csq[code] - 2.0f * s;
                u64 key = ((u64)mono(ed) << 32) | (u32)code;
                atomicMin((unsigned long long*)&finalkey[rl], (unsigned long long)key);
            }
        }
    }
    __syncthreads();

    // ---- finalize: indices, gather, straight-through output, loss ----
    if (t < 64) {
        u32 code = (u32)finalkey[t];
        rowkeyW[1][t] = code;
        out[ZQ_SZ + 1 + n0 + t] = (float)code;
    }
    __syncthreads();
    float* Wg = (float*)&Wb[0][0];       // reuse W buffer: [64][ZSTR] fp32
    {
        int r = t >> 2, c0 = (t & 3) * 32;
        const float4* wr = (const float4*)(wgt + (size_t)rowkeyW[1][r] * DCH + c0);
        float4* dst = (float4*)&Wg[r * ZSTR + c0];
        #pragma unroll
        for (int m = 0; m < 8; ++m) dst[m] = wr[m];
    }
    __syncthreads();
    {
        float* ob = out + (size_t)b * DCH * HW + hw0;
        float sq = 0.f;
        #pragma unroll
        for (int j = 0; j < 32; ++j) {
            int c = w * 32 + j;
            float zv = ztl[p * ZSTR + c];
            float diff = Wg[p * ZSTR + c] - zv;
            ob[(size_t)c * HW + p] = zv + diff;   // straight-through forward value
            sq += diff * diff;
        }
        #pragma unroll
        for (int o = 32; o > 0; o >>= 1) sq += __shfl_down(sq, o, 64);
        if (lane == 0) lsum[w] = sq;
    }
    __syncthreads();
    if (t == 0)
        atomicAdd(out + ZQ_SZ, (lsum[0] + lsum[1] + lsum[2] + lsum[3]) * (BETA / (float)ZQ_SZ));
}

extern "C" void kernel_launch(void* const* d_in, const int* in_sizes, int n_in,
                              void* d_out, int out_size, void* d_ws, size_t ws_size,
                              hipStream_t stream) {
    const float* z = (const float*)d_in[0];
    const float* w = (const float*)d_in[1];
    float* out = (float*)d_out;
    float* wsf = (float*)d_ws;

    // ws layout (floats): wb u16[1048576] = 524288 floats | csq[8192]
    u16* wb = (u16*)wsf;
    float* csq = wsf + 524288;

    kwprep<<<512, 256, 0, stream>>>(w, wb, csq);
    hipMemsetAsync(out + ZQ_SZ, 0, 4, stream);      // zero the loss slot
    kmain<<<256, 256, 0, stream>>>(z, w, wb, csq, out);
}

// Round 4
// 200.174 us; speedup vs baseline: 54.7874x; 1.2906x over previous
//
#include <hip/hip_runtime.h>
#include <hip/hip_bf16.h>

typedef unsigned int u32;
typedef unsigned long long u64;
typedef unsigned short u16;

#define NPOS 16384      // B*H*W
#define DCH  128
#define KCB  8192
#define HW   1024
#define BETA 0.25f
#define ZQ_SZ 2097152
#define MARGIN 0.022f   // >= 2*delta_bf16 (0.0157) + headroom; dists not quantized now
#define QCAP 8192
#define ZSTR 132        // zt LDS row stride in floats (16B aligned, padded)

typedef __attribute__((ext_vector_type(8))) short short8;
typedef __attribute__((ext_vector_type(4))) float f32x4;

__device__ inline u16 f2bf(float x) {   // RNE float->bf16
    u32 u = __float_as_uint(x);
    return (u16)((u + 0x7FFFu + ((u >> 16) & 1u)) >> 16);
}
__device__ inline u32 mono(float f) {   // monotone float->u32 (handles negatives)
    u32 b = __float_as_uint(f);
    return (b & 0x80000000u) ? ~b : (b | 0x80000000u);
}

// ---------------- codebook prep: bf16 convert + squared norms ----------------
__global__ __launch_bounds__(256) void kwprep(const float* __restrict__ w,
                                              u16* __restrict__ wb,
                                              float* __restrict__ csq) {
    const int t = threadIdx.x;
    const int row = blockIdx.x * 16 + (t >> 4);
    const int l = t & 15;
    const float4* src = (const float4*)(w + (size_t)row * DCH + l * 8);
    float4 a = src[0], b = src[1];
    float s = a.x*a.x + a.y*a.y + a.z*a.z + a.w*a.w
            + b.x*b.x + b.y*b.y + b.z*b.z + b.w*b.w;
    union { u16 h[8]; uint4 v; } u;
    u.h[0]=f2bf(a.x); u.h[1]=f2bf(a.y); u.h[2]=f2bf(a.z); u.h[3]=f2bf(a.w);
    u.h[4]=f2bf(b.x); u.h[5]=f2bf(b.y); u.h[6]=f2bf(b.z); u.h[7]=f2bf(b.w);
    *(uint4*)(wb + (size_t)row * DCH + l * 8) = u.v;
    s += __shfl_xor(s, 1, 64);
    s += __shfl_xor(s, 2, 64);
    s += __shfl_xor(s, 4, 64);
    s += __shfl_xor(s, 8, 64);
    if (l == 0) csq[row] = s;
}

// ---- fused main: normalize + barrier-free single-sweep argmin + repair + outputs ----
__global__ __launch_bounds__(256, 2) void kmain(const float* __restrict__ z,
                                                const float* __restrict__ wgt,
                                                const u16* __restrict__ wb,
                                                const float* __restrict__ csq,
                                                float* __restrict__ out) {
    __shared__ __align__(16) float ztl[64 * ZSTR];    // 33.8 KB fp32 normalized rows
    __shared__ __align__(16) u32 shpool[64 * ZSTR];   // 33.8 KB: queue, then reused as Wg
    __shared__ u32 rowMinU[64];                       // running per-row min (f32 bits)
    __shared__ u64 finalkey[64];
    __shared__ float psum[64][4];
    __shared__ float invL[64];
    __shared__ int codes[64];
    __shared__ float lsum[4];
    __shared__ int qcnt;

    const int t = threadIdx.x;
    const int lane = t & 63;
    const int w = t >> 6;                 // wave id 0..3 (owns cols w*32..w*32+31)
    const int n0 = blockIdx.x * 64;
    const int b = n0 >> 10, hw0 = n0 & 1023;

    // ---- phase 0: load + l2-normalize this block's 64 rows into LDS ----
    const int p = lane;
    float vch[32];
    {
        const float* zp = z + (size_t)b * DCH * HW + hw0 + p;
        #pragma unroll
        for (int j = 0; j < 32; ++j)
            vch[j] = zp[(size_t)(w * 32 + j) * HW];
        float s = 0.f;
        #pragma unroll
        for (int j = 0; j < 32; ++j) s += vch[j] * vch[j];
        psum[p][w] = s;
    }
    if (t < 64) { rowMinU[t] = 0x7f800000u; finalkey[t] = ~0ULL; }
    if (t == 0) qcnt = 0;
    __syncthreads();
    if (t < 64) {
        float ss = psum[t][0] + psum[t][1] + psum[t][2] + psum[t][3];
        invL[t] = 1.0f / fmaxf(sqrtf(ss), 1e-12f);
    }
    __syncthreads();
    {
        float inv = invL[p];
        #pragma unroll
        for (int j = 0; j < 32; ++j)
            ztl[p * ZSTR + w * 32 + j] = vch[j] * inv;
    }
    __syncthreads();

    // ---- A fragments (bf16) in registers: row = lane&15, k = (lane>>4)*8+j ----
    short8 af[4][4];
    #pragma unroll
    for (int rt = 0; rt < 4; ++rt)
        #pragma unroll
        for (int ks = 0; ks < 4; ++ks) {
            int row = rt * 16 + (lane & 15);
            int kb = ks * 32 + (lane >> 4) * 8;
            const float4* zr = (const float4*)&ztl[row * ZSTR + kb];
            float4 x0 = zr[0], x1 = zr[1];
            union { u16 h[8]; short8 v; } uu;
            uu.h[0]=f2bf(x0.x); uu.h[1]=f2bf(x0.y); uu.h[2]=f2bf(x0.z); uu.h[3]=f2bf(x0.w);
            uu.h[4]=f2bf(x1.x); uu.h[5]=f2bf(x1.y); uu.h[6]=f2bf(x1.z); uu.h[7]=f2bf(x1.w);
            af[rt][ks] = uu.v;
        }

    // per-thread B base: code = kt*128 + w*32 + (lane&15) (+16 for ct=1), k = (lane>>4)*8
    const u16* wtb = wb + ((w * 32 + (lane & 15)) << 7) + ((lane >> 4) << 3);

    float bmin[16], thr[16];
    #pragma unroll
    for (int i = 0; i < 16; ++i) { bmin[i] = 3.4e38f; thr[i] = -1.f; }

    short8 bA[8], bB[8];

#define LOADB(D, KT) do { \
    const u16* bsrc = wtb + (size_t)(KT) * 16384; \
    _Pragma("unroll") \
    for (int ct_ = 0; ct_ < 2; ++ct_) \
        _Pragma("unroll") \
        for (int ks_ = 0; ks_ < 4; ++ks_) \
            D[ct_ * 4 + ks_] = *(const short8*)(bsrc + ct_ * 2048 + ks_ * 32); \
} while (0)

#define COMPUTE(S, KT, COLLECT) do { \
    f32x4 acc[4][2] = {}; \
    _Pragma("unroll") \
    for (int ks_ = 0; ks_ < 4; ++ks_) \
        _Pragma("unroll") \
        for (int rt_ = 0; rt_ < 4; ++rt_) { \
            acc[rt_][0] = __builtin_amdgcn_mfma_f32_16x16x32_bf16(af[rt_][ks_], S[ks_],     acc[rt_][0], 0, 0, 0); \
            acc[rt_][1] = __builtin_amdgcn_mfma_f32_16x16x32_bf16(af[rt_][ks_], S[4 + ks_], acc[rt_][1], 0, 0, 0); \
        } \
    _Pragma("unroll") \
    for (int rt_ = 0; rt_ < 4; ++rt_) \
        _Pragma("unroll") \
        for (int e_ = 0; e_ < 4; ++e_) { \
            float d0 = fmaf(acc[rt_][0][e_], -2.f, 2.125f); \
            float d1 = fmaf(acc[rt_][1][e_], -2.f, 2.125f); \
            float m2 = fminf(d0, d1); \
            int i_ = rt_ * 4 + e_; \
            bmin[i_] = fminf(bmin[i_], m2); \
            if (COLLECT && m2 <= thr[i_]) { \
                u32 rl = (u32)(rt_ * 16 + (lane >> 4) * 4 + e_); \
                u32 cb = (u32)((KT) * 128 + w * 32 + (lane & 15)); \
                if (d0 <= thr[i_]) { int qi = atomicAdd(&qcnt, 1); if (qi < QCAP) shpool[qi] = (rl << 13) | cb; } \
                if (d1 <= thr[i_]) { int qi = atomicAdd(&qcnt, 1); if (qi < QCAP) shpool[qi] = (rl << 13) | (cb + 16u); } \
            } \
        } \
} while (0)

#define REFRESH() do { \
    _Pragma("unroll") \
    for (int i_ = 0; i_ < 16; ++i_) { \
        float v_ = bmin[i_]; \
        v_ = fminf(v_, __shfl_xor(v_, 1, 64)); \
        v_ = fminf(v_, __shfl_xor(v_, 2, 64)); \
        v_ = fminf(v_, __shfl_xor(v_, 4, 64)); \
        v_ = fminf(v_, __shfl_xor(v_, 8, 64)); \
        if ((lane & 15) == 0) \
            atomicMin(&rowMinU[(i_ >> 2) * 16 + (lane >> 4) * 4 + (i_ & 3)], __float_as_uint(v_)); \
    } \
    _Pragma("unroll") \
    for (int i_ = 0; i_ < 16; ++i_) \
        thr[i_] = fminf(__uint_as_float(rowMinU[(i_ >> 2) * 16 + (lane >> 4) * 4 + (i_ & 3)]), bmin[i_]) + MARGIN; \
} while (0)

    // prologue: evaluate tile 0 (no collection) to seed thresholds
    LOADB(bA, 0);
    COMPUTE(bA, 0, false);
    REFRESH();

    // barrier-free main sweep: 64 k-tiles, depth-1 register prefetch
    #pragma unroll 1
    for (int kt2 = 0; kt2 < 32; ++kt2) {
        const int kt0 = kt2 * 2;
        LOADB(bB, kt0 + 1);
        COMPUTE(bA, kt0, true);
        LOADB(bA, (kt0 + 2) & 63);
        COMPUTE(bB, kt0 + 1, true);
        if ((kt2 & 3) == 3) REFRESH();   // every 8 k-tiles
    }

    __syncthreads();

    // ---- exact fp32 repair: one candidate per 16-lane group ----
    {
        int nq = qcnt < QCAP ? qcnt : QCAP;
        int gq = t >> 4, l = t & 15;
        for (int qi = gq; qi < nq; qi += 16) {
            u32 e = shpool[qi];
            int rl = e >> 13;
            int code = e & 0x1FFF;
            const float4* zr = (const float4*)&ztl[rl * ZSTR + l * 8];
            const float4* wr = (const float4*)(wgt + (size_t)code * DCH + l * 8);
            float4 za = zr[0], zb = zr[1], wa = wr[0], wbv = wr[1];
            float s = 0.f;
            s = fmaf(za.x, wa.x, s); s = fmaf(za.y, wa.y, s);
            s = fmaf(za.z, wa.z, s); s = fmaf(za.w, wa.w, s);
            s = fmaf(zb.x, wbv.x, s); s = fmaf(zb.y, wbv.y, s);
            s = fmaf(zb.z, wbv.z, s); s = fmaf(zb.w, wbv.w, s);
            s += __shfl_xor(s, 1, 64);
            s += __shfl_xor(s, 2, 64);
            s += __shfl_xor(s, 4, 64);
            s += __shfl_xor(s, 8, 64);
            if (l == 0) {
                float ed = csq[code] - 2.0f * s;
                u64 key = ((u64)mono(ed) << 32) | (u32)code;
                atomicMin((unsigned long long*)&finalkey[rl], (unsigned long long)key);
            }
        }
    }
    __syncthreads();

    // ---- finalize: indices, gather (reuse shpool as Wg), straight-through, loss ----
    if (t < 64) {
        u32 code = (u32)finalkey[t];
        codes[t] = (int)code;
        out[ZQ_SZ + 1 + n0 + t] = (float)code;
    }
    __syncthreads();
    float* Wg = (float*)shpool;          // [64][ZSTR] fp32
    {
        int r = t >> 2, c0 = (t & 3) * 32;
        const float4* wr = (const float4*)(wgt + (size_t)codes[r] * DCH + c0);
        float4* dst = (float4*)&Wg[r * ZSTR + c0];
        #pragma unroll
        for (int m = 0; m < 8; ++m) dst[m] = wr[m];
    }
    __syncthreads();
    {
        float* ob = out + (size_t)b * DCH * HW + hw0;
        float sq = 0.f;
        #pragma unroll
        for (int j = 0; j < 32; ++j) {
            int c = w * 32 + j;
            float zv = ztl[p * ZSTR + c];
            float diff = Wg[p * ZSTR + c] - zv;
            ob[(size_t)c * HW + p] = zv + diff;   // straight-through forward value
            sq += diff * diff;
        }
        #pragma unroll
        for (int o = 32; o > 0; o >>= 1) sq += __shfl_down(sq, o, 64);
        if (lane == 0) lsum[w] = sq;
    }
    __syncthreads();
    if (t == 0)
        atomicAdd(out + ZQ_SZ, (lsum[0] + lsum[1] + lsum[2] + lsum[3]) * (BETA / (float)ZQ_SZ));

#undef LOADB
#undef COMPUTE
#undef REFRESH
}

extern "C" void kernel_launch(void* const* d_in, const int* in_sizes, int n_in,
                              void* d_out, int out_size, void* d_ws, size_t ws_size,
                              hipStream_t stream) {
    const float* z = (const float*)d_in[0];
    const float* w = (const float*)d_in[1];
    float* out = (float*)d_out;
    float* wsf = (float*)d_ws;

    // ws layout: wb u16[1048576] (= 524288 floats) | csq f32[8192]
    u16* wb = (u16*)wsf;
    float* csq = wsf + 524288;

    kwprep<<<512, 256, 0, stream>>>(w, wb, csq);
    hipMemsetAsync(out + ZQ_SZ, 0, 4, stream);      // zero the loss slot
    kmain<<<256, 256, 0, stream>>>(z, w, wb, csq, out);
}